// Round 9
// baseline (226.236 us; speedup 1.0000x reference)
//
#include <hip/hip_runtime.h>
#include <cstdint>

#define TPB  512
#define ROWS 32
#define GRID 768

typedef __attribute__((ext_vector_type(8))) short  short8;
typedef __attribute__((ext_vector_type(8))) __bf16 bf16x8;
typedef __attribute__((ext_vector_type(4))) float  f32x4;
typedef __attribute__((ext_vector_type(4))) short  short4v;

__device__ __forceinline__ short f2bf(float f) {
    union { float f; unsigned int u; } v; v.f = f;
    unsigned int u = v.u;
    u += 0x7fffu + ((u >> 16) & 1u);
    return (short)(u >> 16);
}
__device__ __forceinline__ float silu_f(float x) { return x / (1.0f + __expf(-x)); }

// ---- LDS: X0 @0 (8K), X1_i @8192*(1+i) (24K) = 32K used; padded to 40960
// (R2's proven 4-per-CU-max / 3-resident geometry). After reg-compute+barrier,
// H0 overlays X0 and H1_i overlays X1_i.
#define RSB 256
#define SMEM_BYTES 40960

__device__ __forceinline__ int swz(int row, int b) { return row * RSB + (b ^ ((row & 7) << 4)); }

// B-fragment (X/H operand): n-row = r0 + (lane&15), k = ks*32 + 8*(lane>>4)+j
__device__ __forceinline__ short8 lds_bfrag(const char* base, int off, int r0, int ks, int lane) {
    int row = r0 + (lane & 15);
    int bi  = ks * 64 + ((lane >> 4) << 4);
    return *(const short8*)(base + off + swz(row, bi));
}

// A-fragment (weight): lane holds W[k = ks*32+8*(lane>>4)+j][u = tile*16 + (lane&15)]
template<bool PACKED>
__device__ __forceinline__ short8 wfrag(const short8* pw, const float* W, int ldn,
                                        int gtile, int ltile, int ks, int lane) {
    if constexpr (PACKED) {
        return pw[(gtile * 4 + ks) * 64 + lane];
    } else {
        const float* p = W + (size_t)(ks * 32 + ((lane >> 4) << 3)) * ldn + ltile * 16 + (lane & 15);
        short8 r;
#pragma unroll
        for (int j = 0; j < 8; ++j) r[j] = f2bf(p[(size_t)j * ldn]);
        return r;
    }
}

__device__ __forceinline__ f32x4 mfma16(short8 a, short8 b, f32x4 c) {
    return __builtin_amdgcn_mfma_f32_16x16x32_bf16(
        __builtin_bit_cast(bf16x8, a), __builtin_bit_cast(bf16x8, b), c, 0, 0, 0);
}

// prep: pack weights to bf16 fragment layout. Tiles: w1s 0..15, w1v 16..23, w2s 24..31, w2v 32..39.
__global__ void prep_pack(const float* __restrict__ w1s, const float* __restrict__ w1v,
                          const float* __restrict__ w2s, const float* __restrict__ w2v,
                          short8* __restrict__ pk) {
    int b = blockIdx.x, t = threadIdx.x;
    int ks = t >> 6, lane = t & 63;
    const float* W; int ldn, lt;
    if (b < 16)      { W = w1s; ldn = 256; lt = b; }
    else if (b < 24) { W = w1v; ldn = 128; lt = b - 16; }
    else if (b < 32) { W = w2s; ldn = 128; lt = b - 24; }
    else             { W = w2v; ldn = 128; lt = b - 32; }
    const float* p = W + (size_t)(ks * 32 + ((lane >> 4) << 3)) * ldn + lt * 16 + (lane & 15);
    short8 r;
#pragma unroll
    for (int j = 0; j < 8; ++j) r[j] = f2bf(p[(size_t)j * ldn]);
    pk[(b * 4 + ks) * 64 + lane] = r;
}

template<bool PACKED>
__global__ __launch_bounds__(TPB, 4) void gnlr_fused_kernel(
    const float* __restrict__ x,
    const float* __restrict__ w1s, const float* __restrict__ w1v,
    const float* __restrict__ w2s, const float* __restrict__ w2v,
    const short8* __restrict__ pw,
    float* __restrict__ out, int n)
{
    __shared__ alignas(16) char sm[SMEM_BYTES];

    const int tid   = threadIdx.x;
    const int lane  = tid & 63;
    const int w     = tid >> 6;              // wave 0..7 owns u-tile c0 = 16w
    const int c0    = w * 16;
    const float INV = 0.08838834764831845f;  // 1/sqrt(128)
    const f32x4 z = { 0.f, 0.f, 0.f, 0.f };
    const int ntile = n >> 5;                // 3125 (n % 32 == 0)

    float4 st[8];                            // staged tile (32 VGPR)

    auto issue = [&](int tile) {             // global -> regs
        const float* xb = x + (size_t)tile * ROWS * 512;
#pragma unroll
        for (int it = 0; it < 2; ++it) {
            int idx = tid + it * TPB;        // 0..1023
            int row = idx >> 5, c4 = (idx & 31) << 2;
            st[it] = *(const float4*)(xb + row * 512 + c4);
        }
#pragma unroll
        for (int it = 0; it < 2; ++it) {
            int idx = tid + it * TPB;
            int row = idx >> 5, grp = idx & 31;
            const float* p = xb + row * 512 + 128 + grp * 12;
            st[2 + it * 3 + 0] = *(const float4*)(p);
            st[2 + it * 3 + 1] = *(const float4*)(p + 4);
            st[2 + it * 3 + 2] = *(const float4*)(p + 8);
        }
    };

    auto writeLDS = [&]() {                  // regs -> bf16 swizzled LDS
#pragma unroll
        for (int it = 0; it < 2; ++it) {
            int idx = tid + it * TPB;
            int row = idx >> 5, c4 = (idx & 31) << 2;
            float4 f = st[it];
            short4v pk;
            pk.x = f2bf(f.x); pk.y = f2bf(f.y); pk.z = f2bf(f.z); pk.w = f2bf(f.w);
            *(short4v*)(sm + swz(row, c4 * 2)) = pk;
        }
#pragma unroll
        for (int it = 0; it < 2; ++it) {
            int idx = tid + it * TPB;
            int row = idx >> 5, grp = idx & 31;
            float4 fa = st[2 + it * 3 + 0], fb = st[2 + it * 3 + 1], fc = st[2 + it * 3 + 2];
            float fv[12] = { fa.x, fa.y, fa.z, fa.w, fb.x, fb.y, fb.z, fb.w, fc.x, fc.y, fc.z, fc.w };
#pragma unroll
            for (int i = 0; i < 3; ++i) {
                short4v pk;
                pk.x = f2bf(fv[i]); pk.y = f2bf(fv[3 + i]); pk.z = f2bf(fv[6 + i]); pk.w = f2bf(fv[9 + i]);
                *(short4v*)(sm + 8192 + i * 8192 + swz(row, grp * 8)) = pk;
            }
        }
    };

    int t = blockIdx.x;
    if (t >= ntile) return;
    issue(t);
    writeLDS();
    __syncthreads();                         // (a) tile visible

    while (true) {
        int tn = t + GRID;
        bool has = (tn < ntile);
        if (has) issue(tn);                  // next tile's loads in flight under compute

        // ---- phase 1 (to regs): s = x0 @ w1_s; h0 packed bf16, g f32 ----
        short4v h0pk[2];
        float   g_reg[2][4];
        {
            short8 bs[4];
#pragma unroll
            for (int ks = 0; ks < 4; ++ks) bs[ks] = wfrag<PACKED>(pw, w1s, 256, w, w, ks, lane);
#pragma unroll
            for (int rt = 0; rt < 2; ++rt) {
                f32x4 acc = z;
#pragma unroll
                for (int ks = 0; ks < 4; ++ks)
                    acc = mfma16(bs[ks], lds_bfrag(sm, 0, rt * 16, ks, lane), acc);
#pragma unroll
                for (int j = 0; j < 4; ++j) h0pk[rt][j] = f2bf(silu_f(acc[j] * INV));
            }
#pragma unroll
            for (int ks = 0; ks < 4; ++ks) bs[ks] = wfrag<PACKED>(pw, w1s, 256, 8 + w, 8 + w, ks, lane);
#pragma unroll
            for (int rt = 0; rt < 2; ++rt) {
                f32x4 acc = z;
#pragma unroll
                for (int ks = 0; ks < 4; ++ks)
                    acc = mfma16(bs[ks], lds_bfrag(sm, 0, rt * 16, ks, lane), acc);
#pragma unroll
                for (int j = 0; j < 4; ++j) g_reg[rt][j] = silu_f(acc[j] * INV);
            }
        }

        // ---- phase 2 (to regs): h1_i = (x1_i @ w1_v) * g, packed bf16 ----
        short4v h1pk[3][2];
        {
            short8 bv[4];
#pragma unroll
            for (int ks = 0; ks < 4; ++ks) bv[ks] = wfrag<PACKED>(pw, w1v, 128, 16 + w, w, ks, lane);
#pragma unroll
            for (int i = 0; i < 3; ++i) {
#pragma unroll
                for (int rt = 0; rt < 2; ++rt) {
                    f32x4 acc = z;
#pragma unroll
                    for (int ks = 0; ks < 4; ++ks)
                        acc = mfma16(bv[ks], lds_bfrag(sm, 8192 + i * 8192, rt * 16, ks, lane), acc);
#pragma unroll
                    for (int j = 0; j < 4; ++j) h1pk[i][rt][j] = f2bf(acc[j] * INV * g_reg[rt][j]);
                }
            }
        }
        __syncthreads();                     // (b) all X reads done

        // ---- overlay writes: H0 -> X0 region, H1_i -> X1_i regions ----
#pragma unroll
        for (int rt = 0; rt < 2; ++rt) {
            int row = rt * 16 + (lane & 15);
            int bi  = 2 * (c0 + ((lane >> 4) << 2));
            *(short4v*)(sm + swz(row, bi)) = h0pk[rt];
#pragma unroll
            for (int i = 0; i < 3; ++i)
                *(short4v*)(sm + 8192 + i * 8192 + swz(row, bi)) = h1pk[i][rt];
        }
        __syncthreads();                     // (c) H visible

        // ---- phase 3: y0 = h0 @ w2_s, y1_i = h1_i @ w2_v -> global ----
        {
            const int row0g = t * ROWS;
            short8 b2[4];
#pragma unroll
            for (int ks = 0; ks < 4; ++ks) b2[ks] = wfrag<PACKED>(pw, w2s, 128, 24 + w, w, ks, lane);
#pragma unroll
            for (int rt = 0; rt < 2; ++rt) {
                f32x4 acc = z;
#pragma unroll
                for (int ks = 0; ks < 4; ++ks)
                    acc = mfma16(b2[ks], lds_bfrag(sm, 0, rt * 16, ks, lane), acc);
                int rg = row0g + rt * 16 + (lane & 15);
                float4 o = { acc[0] * INV, acc[1] * INV, acc[2] * INV, acc[3] * INV };
                *(float4*)(out + (size_t)rg * 512 + c0 + ((lane >> 4) << 2)) = o;
            }
#pragma unroll
            for (int ks = 0; ks < 4; ++ks) b2[ks] = wfrag<PACKED>(pw, w2v, 128, 32 + w, w, ks, lane);
#pragma unroll
            for (int rt = 0; rt < 2; ++rt) {
                f32x4 a3[3];
#pragma unroll
                for (int i = 0; i < 3; ++i) {
                    a3[i] = z;
#pragma unroll
                    for (int ks = 0; ks < 4; ++ks)
                        a3[i] = mfma16(b2[ks], lds_bfrag(sm, 8192 + i * 8192, rt * 16, ks, lane), a3[i]);
                }
                int rg = row0g + rt * 16 + (lane & 15);
                float* base = out + (size_t)rg * 512 + 128 + 3 * (c0 + ((lane >> 4) << 2));
                float4 s0 = { a3[0][0] * INV, a3[1][0] * INV, a3[2][0] * INV, a3[0][1] * INV };
                float4 s1 = { a3[1][1] * INV, a3[2][1] * INV, a3[0][2] * INV, a3[1][2] * INV };
                float4 s2 = { a3[2][2] * INV, a3[0][3] * INV, a3[1][3] * INV, a3[2][3] * INV };
                *(float4*)(base + 0) = s0;
                *(float4*)(base + 4) = s1;
                *(float4*)(base + 8) = s2;
            }
        }

        if (!has) break;
        __syncthreads();                     // (d) p3 LDS reads done
        writeLDS();                          // stage next tile over X regions
        __syncthreads();                     // (a') next tile visible
        t = tn;
    }
}

extern "C" void kernel_launch(void* const* d_in, const int* in_sizes, int n_in,
                              void* d_out, int out_size, void* d_ws, size_t ws_size,
                              hipStream_t stream) {
    const float* x   = (const float*)d_in[0];
    const float* w1s = (const float*)d_in[1];
    const float* w1v = (const float*)d_in[2];
    const float* w2s = (const float*)d_in[3];
    const float* w2v = (const float*)d_in[4];
    float* out = (float*)d_out;
    const int n = in_sizes[0] / 512;
    const size_t need = (size_t)40 * 4 * 64 * sizeof(short8);  // 163840 B
    if (ws_size >= need) {
        prep_pack<<<40, 256, 0, stream>>>(w1s, w1v, w2s, w2v, (short8*)d_ws);
        gnlr_fused_kernel<true><<<GRID, TPB, 0, stream>>>(x, w1s, w1v, w2s, w2v,
                                                          (const short8*)d_ws, out, n);
    } else {
        gnlr_fused_kernel<false><<<GRID, TPB, 0, stream>>>(x, w1s, w1v, w2s, w2v,
                                                           nullptr, out, n);
    }
}

// Round 10
// 103.867 us; speedup vs baseline: 2.1781x; 2.1781x over previous
//
#include <hip/hip_runtime.h>
#include <cstdint>

#define TPB   512
#define ROWS  32
#define DELTA 1024

typedef __attribute__((ext_vector_type(8))) short  short8;
typedef __attribute__((ext_vector_type(8))) __bf16 bf16x8;
typedef __attribute__((ext_vector_type(4))) float  f32x4;
typedef __attribute__((ext_vector_type(4))) short  short4v;

__device__ __forceinline__ short f2bf(float f) {
    union { float f; unsigned int u; } v; v.f = f;
    unsigned int u = v.u;
    u += 0x7fffu + ((u >> 16) & 1u);
    return (short)(u >> 16);
}
__device__ __forceinline__ float silu_f(float x) { return x / (1.0f + __expf(-x)); }

// ---- LDS (R2 layout, 40960 B): X0 @0 (8K), X1_i @8192*(1+i) (24K), H0 @32768 (8K)
#define RSB 256
#define OFF_H0 32768
#define SMEM_BYTES 40960

__device__ __forceinline__ int swz(int row, int b) { return row * RSB + (b ^ ((row & 7) << 4)); }

// B-fragment (X/H operand): n-row = r0 + (lane&15), k = ks*32 + 8*(lane>>4)+j
__device__ __forceinline__ short8 lds_bfrag(const char* base, int off, int r0, int ks, int lane) {
    int row = r0 + (lane & 15);
    int bi  = ks * 64 + ((lane >> 4) << 4);
    return *(const short8*)(base + off + swz(row, bi));
}

// A-fragment (weight): lane holds W[k = ks*32+8*(lane>>4)+j][u = tile*16 + (lane&15)]
template<bool PACKED>
__device__ __forceinline__ short8 wfrag(const short8* pw, const float* W, int ldn,
                                        int gtile, int ltile, int ks, int lane) {
    if constexpr (PACKED) {
        return pw[(gtile * 4 + ks) * 64 + lane];
    } else {
        const float* p = W + (size_t)(ks * 32 + ((lane >> 4) << 3)) * ldn + ltile * 16 + (lane & 15);
        short8 r;
#pragma unroll
        for (int j = 0; j < 8; ++j) r[j] = f2bf(p[(size_t)j * ldn]);
        return r;
    }
}

__device__ __forceinline__ f32x4 mfma16(short8 a, short8 b, f32x4 c) {
    return __builtin_amdgcn_mfma_f32_16x16x32_bf16(
        __builtin_bit_cast(bf16x8, a), __builtin_bit_cast(bf16x8, b), c, 0, 0, 0);
}

// prep: pack weights to bf16 fragment layout. Tiles: w1s 0..15, w1v 16..23, w2s 24..31, w2v 32..39.
__global__ void prep_pack(const float* __restrict__ w1s, const float* __restrict__ w1v,
                          const float* __restrict__ w2s, const float* __restrict__ w2v,
                          short8* __restrict__ pk) {
    int b = blockIdx.x, t = threadIdx.x;
    int ks = t >> 6, lane = t & 63;
    const float* W; int ldn, lt;
    if (b < 16)      { W = w1s; ldn = 256; lt = b; }
    else if (b < 24) { W = w1v; ldn = 128; lt = b - 16; }
    else if (b < 32) { W = w2s; ldn = 128; lt = b - 24; }
    else             { W = w2v; ldn = 128; lt = b - 32; }
    const float* p = W + (size_t)(ks * 32 + ((lane >> 4) << 3)) * ldn + lt * 16 + (lane & 15);
    short8 r;
#pragma unroll
    for (int j = 0; j < 8; ++j) r[j] = f2bf(p[(size_t)j * ldn]);
    pk[(b * 4 + ks) * 64 + lane] = r;
}

template<bool PACKED>
__global__ __launch_bounds__(TPB, 8) void gnlr_fused_kernel(
    const float* __restrict__ x,
    const float* __restrict__ w1s, const float* __restrict__ w1v,
    const float* __restrict__ w2s, const float* __restrict__ w2v,
    const short8* __restrict__ pw,
    float* __restrict__ out, int n)
{
    __shared__ alignas(16) char sm[SMEM_BYTES];

    const int tid   = threadIdx.x;
    const int lane  = tid & 63;
    const int w     = tid >> 6;              // wave 0..7 owns u-tile c0 = 16w
    const int c0    = w * 16;
    const int row0g = blockIdx.x * ROWS;
    const float INV = 0.08838834764831845f;  // 1/sqrt(128)
    const f32x4 z = { 0.f, 0.f, 0.f, 0.f };
    const int ntile = n >> 5;                // 3125

    // ---- L3 prefetch: tile b+DELTA, one dword per 128B line (64KB coverage) ----
    float pf = 0.f;
    const int tpre = blockIdx.x + DELTA;
    if (tpre < ntile)
        pf = *(x + (size_t)tpre * ROWS * 512 + tid * 32);

    // ---------------- stage x -> LDS (bf16, swizzled) ----------------
#pragma unroll
    for (int it = 0; it < 2; ++it) {
        int idx = tid + it * TPB;            // 0..1023
        int row = idx >> 5;
        int c4  = (idx & 31) << 2;
        int rg  = row0g + row; if (rg >= n) rg = n - 1;
        float4 f = *(const float4*)(x + (size_t)rg * 512 + c4);
        short4v pkv;
        pkv.x = f2bf(f.x); pkv.y = f2bf(f.y); pkv.z = f2bf(f.z); pkv.w = f2bf(f.w);
        *(short4v*)(sm + swz(row, c4 * 2)) = pkv;
    }
#pragma unroll
    for (int it = 0; it < 2; ++it) {
        int idx = tid + it * TPB;
        int row = idx >> 5;
        int grp = idx & 31;                  // u = grp*4 .. grp*4+3
        int rg  = row0g + row; if (rg >= n) rg = n - 1;
        const float* p = x + (size_t)rg * 512 + 128 + grp * 12;
        float4 fa = *(const float4*)(p);
        float4 fb = *(const float4*)(p + 4);
        float4 fc = *(const float4*)(p + 8);
        float f[12] = { fa.x, fa.y, fa.z, fa.w, fb.x, fb.y, fb.z, fb.w, fc.x, fc.y, fc.z, fc.w };
#pragma unroll
        for (int i = 0; i < 3; ++i) {
            short4v pkv;
            pkv.x = f2bf(f[i]); pkv.y = f2bf(f[3 + i]); pkv.z = f2bf(f[6 + i]); pkv.w = f2bf(f[9 + i]);
            *(short4v*)(sm + 8192 + i * 8192 + swz(row, grp * 8)) = pkv;
        }
    }
    asm volatile("" :: "v"(pf));             // keep prefetch live (rule #17); barrier drains anyway
    __syncthreads();

    // ---------------- phase 1: s = x0 @ w1_s (W as A-op, D transposed) ----------------
    float g_reg[2][4];
    {
        short8 bs[4];
#pragma unroll
        for (int ks = 0; ks < 4; ++ks) bs[ks] = wfrag<PACKED>(pw, w1s, 256, w, w, ks, lane);
#pragma unroll
        for (int rt = 0; rt < 2; ++rt) {
            f32x4 acc = z;
#pragma unroll
            for (int ks = 0; ks < 4; ++ks)
                acc = mfma16(bs[ks], lds_bfrag(sm, 0, rt * 16, ks, lane), acc);
            short4v pkv;
#pragma unroll
            for (int j = 0; j < 4; ++j) pkv[j] = f2bf(silu_f(acc[j] * INV));
            int row = rt * 16 + (lane & 15);
            *(short4v*)(sm + OFF_H0 + swz(row, 2 * (c0 + ((lane >> 4) << 2)))) = pkv;
        }
#pragma unroll
        for (int ks = 0; ks < 4; ++ks) bs[ks] = wfrag<PACKED>(pw, w1s, 256, 8 + w, 8 + w, ks, lane);
#pragma unroll
        for (int rt = 0; rt < 2; ++rt) {
            f32x4 acc = z;
#pragma unroll
            for (int ks = 0; ks < 4; ++ks)
                acc = mfma16(bs[ks], lds_bfrag(sm, 0, rt * 16, ks, lane), acc);
#pragma unroll
            for (int j = 0; j < 4; ++j) g_reg[rt][j] = silu_f(acc[j] * INV);
        }
    }

    // ---------------- phase 2: h1_i = (x1_i @ w1_v) * g -> overlay region i*8192 ----------------
    {
        short8 bv[4];
#pragma unroll
        for (int ks = 0; ks < 4; ++ks) bv[ks] = wfrag<PACKED>(pw, w1v, 128, 16 + w, w, ks, lane);
#pragma unroll
        for (int i = 0; i < 3; ++i) {
            __syncthreads();                 // prior readers of overlay target done
#pragma unroll
            for (int rt = 0; rt < 2; ++rt) {
                f32x4 acc = z;
#pragma unroll
                for (int ks = 0; ks < 4; ++ks)
                    acc = mfma16(bv[ks], lds_bfrag(sm, 8192 + i * 8192, rt * 16, ks, lane), acc);
                short4v pkv;
#pragma unroll
                for (int j = 0; j < 4; ++j) pkv[j] = f2bf(acc[j] * INV * g_reg[rt][j]);
                int row = rt * 16 + (lane & 15);
                *(short4v*)(sm + i * 8192 + swz(row, 2 * (c0 + ((lane >> 4) << 2)))) = pkv;
            }
        }
    }
    __syncthreads();

    // ---------------- phase 3: y0 = h0 @ w2_s, y1_i = h1_i @ w2_v -> global ----------------
    {
        short8 b2[4];
#pragma unroll
        for (int ks = 0; ks < 4; ++ks) b2[ks] = wfrag<PACKED>(pw, w2s, 128, 24 + w, w, ks, lane);
#pragma unroll
        for (int rt = 0; rt < 2; ++rt) {
            f32x4 acc = z;
#pragma unroll
            for (int ks = 0; ks < 4; ++ks)
                acc = mfma16(b2[ks], lds_bfrag(sm, OFF_H0, rt * 16, ks, lane), acc);
            int rg = row0g + rt * 16 + (lane & 15);
            if (rg < n) {
                float4 o = { acc[0] * INV, acc[1] * INV, acc[2] * INV, acc[3] * INV };
                *(float4*)(out + (size_t)rg * 512 + c0 + ((lane >> 4) << 2)) = o;
            }
        }
#pragma unroll
        for (int ks = 0; ks < 4; ++ks) b2[ks] = wfrag<PACKED>(pw, w2v, 128, 32 + w, w, ks, lane);
#pragma unroll
        for (int rt = 0; rt < 2; ++rt) {
            f32x4 a3[3];
#pragma unroll
            for (int i = 0; i < 3; ++i) {
                a3[i] = z;
#pragma unroll
                for (int ks = 0; ks < 4; ++ks)
                    a3[i] = mfma16(b2[ks], lds_bfrag(sm, i * 8192, rt * 16, ks, lane), a3[i]);
            }
            int rg = row0g + rt * 16 + (lane & 15);
            if (rg < n) {
                float* base = out + (size_t)rg * 512 + 128 + 3 * (c0 + ((lane >> 4) << 2));
                float4 s0 = { a3[0][0] * INV, a3[1][0] * INV, a3[2][0] * INV, a3[0][1] * INV };
                float4 s1 = { a3[1][1] * INV, a3[2][1] * INV, a3[0][2] * INV, a3[1][2] * INV };
                float4 s2 = { a3[2][2] * INV, a3[0][3] * INV, a3[1][3] * INV, a3[2][3] * INV };
                *(float4*)(base + 0) = s0;
                *(float4*)(base + 4) = s1;
                *(float4*)(base + 8) = s2;
            }
        }
    }
}

extern "C" void kernel_launch(void* const* d_in, const int* in_sizes, int n_in,
                              void* d_out, int out_size, void* d_ws, size_t ws_size,
                              hipStream_t stream) {
    const float* x   = (const float*)d_in[0];
    const float* w1s = (const float*)d_in[1];
    const float* w1v = (const float*)d_in[2];
    const float* w2s = (const float*)d_in[3];
    const float* w2v = (const float*)d_in[4];
    float* out = (float*)d_out;
    const int n = in_sizes[0] / 512;
    const int grid = (n + ROWS - 1) / ROWS;
    const size_t need = (size_t)40 * 4 * 64 * sizeof(short8);  // 163840 B
    if (ws_size >= need) {
        prep_pack<<<40, 256, 0, stream>>>(w1s, w1v, w2s, w2v, (short8*)d_ws);
        gnlr_fused_kernel<true><<<grid, TPB, 0, stream>>>(x, w1s, w1v, w2s, w2v,
                                                          (const short8*)d_ws, out, n);
    } else {
        gnlr_fused_kernel<false><<<grid, TPB, 0, stream>>>(x, w1s, w1v, w2s, w2v,
                                                           nullptr, out, n);
    }
}